// Round 1
// baseline (1223.012 us; speedup 1.0000x reference)
//
#include <hip/hip_runtime.h>

// Problem constants
#define NK 19                 // classes
#define NC 64                 // channels
#define HW (512*512)          // pixels per (batch, channel) plane
#define NB 8                  // batches
#define BLOCK 256
#define PIX_PER_BLOCK 1024    // 256 threads * 4 pixels
#define NBLOCKS ((NB*HW)/PIX_PER_BLOCK)   // 2048
#define NCOPIES 16            // rotating global accumulator copies
#define SUMS (NK*NC)          // 1216
#define COPY_STRIDE 1280      // floats per copy: 1216 sums + 19 counts + pad

// ---------------------------------------------------------------------------
// Kernel 1: scatter-accumulate per-class feature sums + counts.
// Layout of LDS accumulator: acc[wave][c*19 + k]  -> for fixed c, the 19
// class slots hit 19 distinct LDS banks (c*19+k mod 32 spreads over k).
// ---------------------------------------------------------------------------
__global__ __launch_bounds__(BLOCK) void accum_kernel(
    const float* __restrict__ x, const int* __restrict__ t,
    float* __restrict__ ws) {
  __shared__ float acc[4][SUMS];   // per-wave private sums
  __shared__ float cnt[4][32];     // per-wave private counts (padded)

  const int tid = threadIdx.x;
  const int wv  = tid >> 6;

  // zero LDS
  for (int i = tid; i < 4 * SUMS; i += BLOCK) ((float*)acc)[i] = 0.0f;
  if (tid < 128) ((float*)cnt)[tid] = 0.0f;
  __syncthreads();

  const int bid   = blockIdx.x;
  const int batch = bid >> 8;                      // 256 blocks per batch
  const int hw    = ((bid & 255) << 10) + (tid << 2);

  // labels for this thread's 4 pixels (coalesced 16B/lane)
  const int4 lbl = *reinterpret_cast<const int4*>(t + (bid << 10) + (tid << 2));
  const int t0 = lbl.x, t1 = lbl.y, t2 = lbl.z, t3 = lbl.w;

  float* cw = cnt[wv];
  atomicAdd(cw + t0, 1.0f);
  atomicAdd(cw + t1, 1.0f);
  atomicAdd(cw + t2, 1.0f);
  atomicAdd(cw + t3, 1.0f);

  // channel-0 address of this thread's 4 pixels; channels are HW apart
  const float4* p0 =
      reinterpret_cast<const float4*>(x + (size_t)batch * (NC * HW) + hw);
  float* aw = acc[wv];

#pragma unroll 2
  for (int c = 0; c < NC; c += 4) {
    float4 v0 = p0[(size_t)(c + 0) * (HW / 4)];
    float4 v1 = p0[(size_t)(c + 1) * (HW / 4)];
    float4 v2 = p0[(size_t)(c + 2) * (HW / 4)];
    float4 v3 = p0[(size_t)(c + 3) * (HW / 4)];
    float* A;
    A = aw + (c + 0) * NK;
    atomicAdd(A + t0, v0.x); atomicAdd(A + t1, v0.y);
    atomicAdd(A + t2, v0.z); atomicAdd(A + t3, v0.w);
    A = aw + (c + 1) * NK;
    atomicAdd(A + t0, v1.x); atomicAdd(A + t1, v1.y);
    atomicAdd(A + t2, v1.z); atomicAdd(A + t3, v1.w);
    A = aw + (c + 2) * NK;
    atomicAdd(A + t0, v2.x); atomicAdd(A + t1, v2.y);
    atomicAdd(A + t2, v2.z); atomicAdd(A + t3, v2.w);
    A = aw + (c + 3) * NK;
    atomicAdd(A + t0, v3.x); atomicAdd(A + t1, v3.y);
    atomicAdd(A + t2, v3.z); atomicAdd(A + t3, v3.w);
  }

  __syncthreads();

  // merge 4 wave regions, flush to one of 16 global copies
  float* base = ws + (size_t)(bid & (NCOPIES - 1)) * COPY_STRIDE;
  for (int i = tid; i < SUMS; i += BLOCK) {
    float s = acc[0][i] + acc[1][i] + acc[2][i] + acc[3][i];
    atomicAdd(base + i, s);
  }
  if (tid < NK) {
    float s = cnt[0][tid] + cnt[1][tid] + cnt[2][tid] + cnt[3][tid];
    atomicAdd(base + SUMS + tid, s);
  }
}

// ---------------------------------------------------------------------------
// Kernel 2: centers -> norms -> 19x19 cosine pairs -> scalar loss
// ---------------------------------------------------------------------------
__global__ __launch_bounds__(512) void finalize_kernel(
    const float* __restrict__ ws, float* __restrict__ out) {
  __shared__ float cen[NC * 20];   // [c][k], padded to 20 for bank spread
  __shared__ float invn[NK];
  __shared__ float cc[NK];
  __shared__ float red[8];

  const int tid = threadIdx.x;

  if (tid < NK) {
    float s = 0.0f;
    for (int r = 0; r < NCOPIES; ++r) s += ws[r * COPY_STRIDE + SUMS + tid];
    cc[tid] = fmaxf(s, 1.0f);
  }
  __syncthreads();

  for (int i = tid; i < SUMS; i += 512) {
    int c = i / NK, k = i - c * NK;
    float s = 0.0f;
    for (int r = 0; r < NCOPIES; ++r) s += ws[r * COPY_STRIDE + i];
    cen[c * 20 + k] = s / cc[k];
  }
  __syncthreads();

  if (tid < NK) {
    float sq = 0.0f;
    for (int c = 0; c < NC; ++c) {
      float v = cen[c * 20 + tid];
      sq += v * v;
    }
    invn[tid] = 1.0f / fmaxf(sqrtf(sq), 1e-8f);
  }
  __syncthreads();

  float contrib = 0.0f;
  if (tid < NK * NK) {
    int i = tid / NK, j = tid - (tid / NK) * NK;
    float dot = 0.0f;
    for (int c = 0; c < NC; ++c) dot += cen[c * 20 + i] * cen[c * 20 + j];
    float S = dot * invn[i] * invn[j];
    contrib = (i == j) ? (1.0f - S) : fmaxf(S, 0.0f);
  }

  // block reduction: wave shuffle then LDS across 8 waves
  for (int off = 32; off > 0; off >>= 1) contrib += __shfl_down(contrib, off, 64);
  if ((tid & 63) == 0) red[tid >> 6] = contrib;
  __syncthreads();
  if (tid == 0) {
    float s = 0.0f;
    for (int w = 0; w < 8; ++w) s += red[w];
    out[0] = s / 6859.0f;  // / K^3
  }
}

extern "C" void kernel_launch(void* const* d_in, const int* in_sizes, int n_in,
                              void* d_out, int out_size, void* d_ws, size_t ws_size,
                              hipStream_t stream) {
  const float* x = (const float*)d_in[0];
  const int*   t = (const int*)d_in[1];
  float* ws = (float*)d_ws;

  hipMemsetAsync(d_ws, 0, (size_t)NCOPIES * COPY_STRIDE * sizeof(float), stream);
  accum_kernel<<<NBLOCKS, BLOCK, 0, stream>>>(x, t, ws);
  finalize_kernel<<<1, 512, 0, stream>>>(ws, (float*)d_out);
}